// Round 1
// baseline (311.287 us; speedup 1.0000x reference)
//
#include <hip/hip_runtime.h>
#include <math.h>

#define DD 256     // feature dim
#define NN 128     // neighbors
#define NB 572     // drugs (batch)
#define KT 32      // k-tile for matmul
#define DRTP 132   // padded row stride for transposed DR tile

// ---------------------------------------------------------------------------
// Main per-drug kernel: logits via (d*r)@W1 collapse, softmax, sparse ent
// gather, fused linear+relu. Writes y (pre-BN) into d_out.
// ---------------------------------------------------------------------------
__global__ __launch_bounds__(256, 2)
void gnn_main(const float* __restrict__ drug_table,
              const float* __restrict__ rela_table,
              const float* __restrict__ ent_table,
              const float* __restrict__ W1,
              const float* __restrict__ b1,
              const float* __restrict__ W2,
              const float* __restrict__ b2,
              const float* __restrict__ lin_w,
              const float* __restrict__ lin_b,
              const int*   __restrict__ drug_name,
              const int*   __restrict__ adj_tail,
              const int*   __restrict__ adj_relation,
              float* __restrict__ Y)
{
    __shared__ float W1_l[KT * DD];      // 32 KB: W1 k-tile [KT][DD]
    __shared__ float DRT_l[KT * DRTP];   // 16.5 KB: DR transposed [KT][128+pad]
    __shared__ float d_l[DD];
    __shared__ float w2s_l[DD];          // row-sums of W2[b]
    __shared__ float b2s_l[NN];          // row-sums of b2
    __shared__ float score_l[NN];        // logits, then softmax scores
    __shared__ float x_l[2 * DD];        // [w_ent | d] for the linear layer
    __shared__ int   rel_l[NN];
    __shared__ int   tail_l[NN];

    const int b    = blockIdx.x;
    const int tid  = threadIdx.x;
    const int lane = tid & 63;
    const int wv   = tid >> 6;

    if (tid < NN) {
        rel_l[tid]  = adj_relation[b * NN + tid];
        tail_l[tid] = adj_tail[b * NN + tid];
    }
    d_l[tid] = drug_table[(size_t)drug_name[b] * DD + tid];

    // b2sum[n] = sum_e b2[n,e]  (wave-per-row, float4 + shfl reduce)
    for (int n = wv; n < NN; n += 4) {
        float4 v = *reinterpret_cast<const float4*>(&b2[n * DD + lane * 4]);
        float s = v.x + v.y + v.z + v.w;
        #pragma unroll
        for (int m = 32; m >= 1; m >>= 1) s += __shfl_xor(s, m, 64);
        if (lane == 0) b2s_l[n] = s;
    }
    // w2sum[d] = sum_e W2[b,d,e]  (collapses the entire second einsum)
    const float* W2b = W2 + (size_t)b * DD * DD;
    for (int d = wv; d < DD; d += 4) {
        float4 v = *reinterpret_cast<const float4*>(&W2b[d * DD + lane * 4]);
        float s = v.x + v.y + v.z + v.w;
        #pragma unroll
        for (int m = 32; m >= 1; m >>= 1) s += __shfl_xor(s, m, 64);
        if (lane == 0) w2s_l[d] = s;
    }
    __syncthreads();

    // ---- A = DR @ W1 + b1, thread tile 8 rows x 16 cols ----
    const int tn = tid >> 4, td = tid & 15;
    const int n0 = tn * 8, c0 = td * 16;
    float acc[8][16];
    #pragma unroll
    for (int r = 0; r < 8; ++r) {
        #pragma unroll
        for (int j = 0; j < 4; ++j) {
            float4 v = *reinterpret_cast<const float4*>(&b1[(n0 + r) * DD + c0 + j * 4]);
            acc[r][j*4+0] = v.x; acc[r][j*4+1] = v.y;
            acc[r][j*4+2] = v.z; acc[r][j*4+3] = v.w;
        }
    }

    const float* W1b = W1 + (size_t)b * DD * DD;
    for (int kt = 0; kt < DD / KT; ++kt) {
        // stage W1 tile [KT][DD] (contiguous 32 KB, float4-coalesced)
        #pragma unroll
        for (int i = 0; i < 8; ++i) {
            int idx = tid + i * 256;
            *reinterpret_cast<float4*>(&W1_l[idx * 4]) =
                *reinterpret_cast<const float4*>(&W1b[(size_t)kt * KT * DD + idx * 4]);
        }
        // stage DR^T tile: DRT[k][n] = d[kt*KT+k] * rela[rel[n]][kt*KT+k]
        {
            int n  = tid >> 1;
            int ks = (tid & 1) * 16;
            const float* rr = rela_table + (size_t)rel_l[n] * DD + kt * KT + ks;
            #pragma unroll
            for (int j = 0; j < 4; ++j) {
                float4 v = *reinterpret_cast<const float4*>(&rr[j * 4]);
                int k = ks + j * 4;
                DRT_l[(k+0) * DRTP + n] = d_l[kt*KT + k+0] * v.x;
                DRT_l[(k+1) * DRTP + n] = d_l[kt*KT + k+1] * v.y;
                DRT_l[(k+2) * DRTP + n] = d_l[kt*KT + k+2] * v.z;
                DRT_l[(k+3) * DRTP + n] = d_l[kt*KT + k+3] * v.w;
            }
        }
        __syncthreads();
        #pragma unroll 2
        for (int k = 0; k < KT; ++k) {
            float4 a0 = *reinterpret_cast<const float4*>(&DRT_l[k * DRTP + n0]);
            float4 a1 = *reinterpret_cast<const float4*>(&DRT_l[k * DRTP + n0 + 4]);
            float aa[8] = {a0.x, a0.y, a0.z, a0.w, a1.x, a1.y, a1.z, a1.w};
            float ww[16];
            #pragma unroll
            for (int j = 0; j < 4; ++j) {
                float4 w4 = *reinterpret_cast<const float4*>(&W1_l[k * DD + c0 + j * 4]);
                ww[j*4+0] = w4.x; ww[j*4+1] = w4.y;
                ww[j*4+2] = w4.z; ww[j*4+3] = w4.w;
            }
            #pragma unroll
            for (int r = 0; r < 8; ++r)
                #pragma unroll
                for (int c = 0; c < 16; ++c)
                    acc[r][c] = fmaf(aa[r], ww[c], acc[r][c]);
        }
        __syncthreads();
    }

    // logit[n] = sum_d' relu(A[n,d']) * w2sum[d'] + b2sum[n]
    float p[8];
    #pragma unroll
    for (int r = 0; r < 8; ++r) {
        float s = 0.f;
        #pragma unroll
        for (int c = 0; c < 16; ++c)
            s += fmaxf(acc[r][c], 0.f) * w2s_l[c0 + c];
        #pragma unroll
        for (int m = 8; m >= 1; m >>= 1) s += __shfl_xor(s, m, 16);
        p[r] = s;
    }
    if (td == 0) {
        #pragma unroll
        for (int r = 0; r < 8; ++r) score_l[n0 + r] = p[r] + b2s_l[n0 + r];
    }
    __syncthreads();

    // softmax over 128 logits (wave 0)
    if (tid < 64) {
        float l0 = score_l[tid], l1 = score_l[tid + 64];
        float M = fmaxf(l0, l1);
        #pragma unroll
        for (int m = 32; m >= 1; m >>= 1) M = fmaxf(M, __shfl_xor(M, m, 64));
        float e0 = expf(l0 - M), e1 = expf(l1 - M);
        float S = e0 + e1;
        #pragma unroll
        for (int m = 32; m >= 1; m >>= 1) S += __shfl_xor(S, m, 64);
        float inv = 1.f / S;
        score_l[tid]      = e0 * inv;
        score_l[tid + 64] = e1 * inv;
    }
    __syncthreads();

    // w_ent = sum_n score[n] * ent_table[tail[n]]; skip negligible scores
    // (softmax is ~one-hot: logit std ~4e3). Skipped mass < 128*1e-9*|e| ~ 1e-6.
    float w = 0.f;
    for (int n = 0; n < NN; ++n) {
        float s = score_l[n];
        if (s > 1e-9f)
            w = fmaf(s, ent_table[(size_t)tail_l[n] * DD + tid], w);
    }
    x_l[tid]      = w;
    x_l[DD + tid] = d_l[tid];
    __syncthreads();

    // y[d'] = relu(x . lin_w[d',:] + lin_b[d'])  (lin_w is L2-resident, 512 KB)
    const float* lw = lin_w + (size_t)tid * (2 * DD);
    float dot = 0.f;
    #pragma unroll 4
    for (int k4 = 0; k4 < (2 * DD) / 4; ++k4) {
        float4 xv = *reinterpret_cast<const float4*>(&x_l[k4 * 4]);
        float4 wv = *reinterpret_cast<const float4*>(&lw[k4 * 4]);
        dot += xv.x * wv.x + xv.y * wv.y + xv.z * wv.z + xv.w * wv.w;
    }
    float y = dot + lin_b[tid];
    Y[(size_t)b * DD + tid] = fmaxf(y, 0.f);
}

// ---------------------------------------------------------------------------
// BN stats: one block per feature, reduce over batch (biased variance)
// ---------------------------------------------------------------------------
__global__ void bn_stats(const float* __restrict__ Y, float* __restrict__ stats)
{
    int d = blockIdx.x, t = threadIdx.x;  // 64 threads
    float s = 0.f, ss = 0.f;
    for (int b = t; b < NB; b += 64) {
        float v = Y[(size_t)b * DD + d];
        s += v; ss += v * v;
    }
    #pragma unroll
    for (int m = 32; m >= 1; m >>= 1) {
        s  += __shfl_xor(s, m, 64);
        ss += __shfl_xor(ss, m, 64);
    }
    if (t == 0) {
        float mean = s * (1.f / NB);
        float var  = ss * (1.f / NB) - mean * mean;
        stats[d]        = mean;
        stats[DD + d]   = rsqrtf(var + 1e-5f);
    }
}

// ---------------------------------------------------------------------------
// BN apply (in-place on d_out, fully coalesced)
// ---------------------------------------------------------------------------
__global__ void bn_apply(float* __restrict__ Y, const float* __restrict__ stats,
                         const float* __restrict__ gamma, const float* __restrict__ beta)
{
    int b = blockIdx.x, t = threadIdx.x;
    float mean = stats[t], inv = stats[DD + t];
    float v = Y[(size_t)b * DD + t];
    Y[(size_t)b * DD + t] = gamma[t] * (v - mean) * inv + beta[t];
}

extern "C" void kernel_launch(void* const* d_in, const int* in_sizes, int n_in,
                              void* d_out, int out_size, void* d_ws, size_t ws_size,
                              hipStream_t stream)
{
    const float* drug_table = (const float*)d_in[0];
    const float* rela_table = (const float*)d_in[1];
    const float* ent_table  = (const float*)d_in[2];
    const float* W1         = (const float*)d_in[3];
    const float* b1         = (const float*)d_in[4];
    const float* W2         = (const float*)d_in[5];
    const float* b2         = (const float*)d_in[6];
    const float* lin_w      = (const float*)d_in[7];
    const float* lin_b      = (const float*)d_in[8];
    const float* bn_g       = (const float*)d_in[9];
    const float* bn_b       = (const float*)d_in[10];
    const int*   drug_name  = (const int*)d_in[11];
    const int*   adj_tail   = (const int*)d_in[12];
    const int*   adj_rel    = (const int*)d_in[13];
    float* out   = (float*)d_out;
    float* stats = (float*)d_ws;   // 512 floats

    gnn_main<<<NB, 256, 0, stream>>>(drug_table, rela_table, ent_table,
                                     W1, b1, W2, b2, lin_w, lin_b,
                                     drug_name, adj_tail, adj_rel, out);
    bn_stats<<<DD, 64, 0, stream>>>(out, stats);
    bn_apply<<<NB, DD, 0, stream>>>(out, stats, bn_g, bn_b);
}

// Round 2
// 226.567 us; speedup vs baseline: 1.3739x; 1.3739x over previous
//
#include <hip/hip_runtime.h>
#include <math.h>

#define DD 256     // feature dim
#define NN 128     // neighbors
#define NB 572     // drugs (batch)
#define KT 32      // k-tile
#define DRTP 128   // row stride of transposed DR tile (conflict-free w/ strided cols)

__device__ __forceinline__ float4 ld4(const float* p) {
    return *reinterpret_cast<const float4*>(p);
}

// ---------------------------------------------------------------------------
// Kernel 1: streaming row-sums. blocks 0..2*NB-1: half of W2[b] each.
// block 2*NB: b2 row-sums. Collapses the entire second einsum:
//   sum_e (h@W2[b]+b2)[n,e] = h[n,:].w2sum[b,:] + b2sum[n]
// ---------------------------------------------------------------------------
__global__ __launch_bounds__(256)
void sum_rows(const float* __restrict__ W2, const float* __restrict__ b2,
              float* __restrict__ w2s, float* __restrict__ b2s)
{
    const int blk  = blockIdx.x;
    const int tid  = threadIdx.x;
    const int lane = tid & 63;
    const int wv   = tid >> 6;

    if (blk < 2 * NB) {
        const int b = blk >> 1, half = blk & 1;
        const float* src = W2 + (size_t)b * DD * DD + (size_t)half * (DD / 2) * DD;
        float* dst = w2s + (size_t)b * DD + half * (DD / 2);
        for (int r = wv; r < DD / 2; r += 4) {
            float4 v = ld4(&src[r * DD + lane * 4]);
            float s = v.x + v.y + v.z + v.w;
            #pragma unroll
            for (int m = 32; m >= 1; m >>= 1) s += __shfl_xor(s, m, 64);
            if (lane == 0) dst[r] = s;
        }
    } else {
        for (int r = wv; r < NN; r += 4) {
            float4 v = ld4(&b2[r * DD + lane * 4]);
            float s = v.x + v.y + v.z + v.w;
            #pragma unroll
            for (int m = 32; m >= 1; m >>= 1) s += __shfl_xor(s, m, 64);
            if (lane == 0) b2s[r] = s;
        }
    }
}

// ---------------------------------------------------------------------------
// Kernel 2: per-drug. A = (d*r)@W1 + b1 (f32 tiled matmul), logits via w2sum
// collapse, softmax, sparse ent gather, fused linear+relu. Writes pre-BN y.
// 512 threads: thread tile 4 rows x 16 cols, cols strided (j*64 + td*4) so
// W1_l fragment reads are 2-way bank aliased (free) instead of 8-way.
// ---------------------------------------------------------------------------
__global__ __launch_bounds__(512, 4)
void gnn_main(const float* __restrict__ drug_table,
              const float* __restrict__ rela_table,
              const float* __restrict__ ent_table,
              const float* __restrict__ W1,
              const float* __restrict__ b1,
              const float* __restrict__ lin_w,
              const float* __restrict__ lin_b,
              const int*   __restrict__ drug_name,
              const int*   __restrict__ adj_tail,
              const int*   __restrict__ adj_relation,
              const float* __restrict__ w2s_g,
              const float* __restrict__ b2s_g,
              float* __restrict__ Y)
{
    __shared__ float W1_l[KT * DD];      // 32 KB
    __shared__ float DRT_l[KT * DRTP];   // 16 KB
    __shared__ float d_l[DD];
    __shared__ float w2s_l[DD];
    __shared__ float b2s_l[NN];
    __shared__ float score_l[NN];
    __shared__ float x_l[2 * DD];
    __shared__ int   rel_l[NN];
    __shared__ int   tail_l[NN];

    const int b   = blockIdx.x;
    const int tid = threadIdx.x;

    // cooperative small loads
    if (tid < DD) {
        d_l[tid]   = drug_table[(size_t)drug_name[b] * DD + tid];
        w2s_l[tid] = w2s_g[(size_t)b * DD + tid];
    } else {
        int t = tid - DD;
        if (t < NN) {
            rel_l[t]  = adj_relation[b * NN + t];
            tail_l[t] = adj_tail[b * NN + t];
        } else {
            b2s_l[t - NN] = b2s_g[t - NN];
        }
    }
    __syncthreads();

    const int tn = tid >> 4;     // 0..31 -> rows n0..n0+3
    const int td = tid & 15;     // 0..15 -> cols j*64 + td*4 + c
    const int n0 = tn * 4;
    const int cb = td * 4;

    float acc[4][16];
    #pragma unroll
    for (int r = 0; r < 4; ++r) {
        #pragma unroll
        for (int j = 0; j < 4; ++j) {
            float4 v = ld4(&b1[(n0 + r) * DD + j * 64 + cb]);
            acc[r][j*4+0] = v.x; acc[r][j*4+1] = v.y;
            acc[r][j*4+2] = v.z; acc[r][j*4+3] = v.w;
        }
    }

    const float* W1b = W1 + (size_t)b * DD * DD;
    const int nst = tid & 127;        // DRT stage: neighbor column
    const int ksh = (tid >> 7) * 8;   // k sub-block

    for (int kt = 0; kt < DD / KT; ++kt) {
        // stage W1 k-tile [KT][DD]: 8192 floats, float4-coalesced
        #pragma unroll
        for (int i = 0; i < 4; ++i) {
            int idx = tid + i * 512;
            *reinterpret_cast<float4*>(&W1_l[idx * 4]) =
                ld4(&W1b[(size_t)kt * KT * DD + idx * 4]);
        }
        // stage DR^T tile: DRT[k][n] = d[kt*KT+k] * rela[rel[n]][kt*KT+k]
        {
            const float* rr = rela_table + (size_t)rel_l[nst] * DD + kt * KT + ksh;
            float4 v0 = ld4(rr), v1 = ld4(rr + 4);
            float vv[8] = {v0.x, v0.y, v0.z, v0.w, v1.x, v1.y, v1.z, v1.w};
            #pragma unroll
            for (int j = 0; j < 8; ++j)
                DRT_l[(ksh + j) * DRTP + nst] = d_l[kt * KT + ksh + j] * vv[j];
        }
        __syncthreads();

        #pragma unroll 4
        for (int k = 0; k < KT; ++k) {
            float4 a = ld4(&DRT_l[k * DRTP + n0]);
            float aa[4] = {a.x, a.y, a.z, a.w};
            float ww[16];
            #pragma unroll
            for (int j = 0; j < 4; ++j) {
                float4 w4 = ld4(&W1_l[k * DD + j * 64 + cb]);
                ww[j*4+0] = w4.x; ww[j*4+1] = w4.y;
                ww[j*4+2] = w4.z; ww[j*4+3] = w4.w;
            }
            #pragma unroll
            for (int r = 0; r < 4; ++r)
                #pragma unroll
                for (int c = 0; c < 16; ++c)
                    acc[r][c] = fmaf(aa[r], ww[c], acc[r][c]);
        }
        __syncthreads();
    }

    // logit[n] = sum_c relu(A[n,c]) * w2sum[c] + b2sum[n]
    #pragma unroll
    for (int r = 0; r < 4; ++r) {
        float s = 0.f;
        #pragma unroll
        for (int j = 0; j < 4; ++j)
            #pragma unroll
            for (int c = 0; c < 4; ++c)
                s += fmaxf(acc[r][j*4+c], 0.f) * w2s_l[j * 64 + cb + c];
        #pragma unroll
        for (int m = 8; m >= 1; m >>= 1) s += __shfl_xor(s, m, 16);
        if (td == 0) score_l[n0 + r] = s + b2s_l[n0 + r];
    }
    __syncthreads();

    // softmax over 128 logits (wave 0)
    if (tid < 64) {
        float l0 = score_l[tid], l1 = score_l[tid + 64];
        float M = fmaxf(l0, l1);
        #pragma unroll
        for (int m = 32; m >= 1; m >>= 1) M = fmaxf(M, __shfl_xor(M, m, 64));
        float e0 = expf(l0 - M), e1 = expf(l1 - M);
        float S = e0 + e1;
        #pragma unroll
        for (int m = 32; m >= 1; m >>= 1) S += __shfl_xor(S, m, 64);
        float inv = 1.f / S;
        score_l[tid]      = e0 * inv;
        score_l[tid + 64] = e1 * inv;
    }
    __syncthreads();

    // w_ent = sum_n score[n] * ent[tail[n]]; skip negligible scores
    // (logit std ~4e3 -> softmax ~one-hot; skipped mass < 128e-9)
    if (tid < DD) {
        float w = 0.f;
        for (int n = 0; n < NN; ++n) {
            float s = score_l[n];
            if (s > 1e-9f)
                w = fmaf(s, ent_table[(size_t)tail_l[n] * DD + tid], w);
        }
        x_l[tid]      = w;
        x_l[DD + tid] = d_l[tid];
    }
    __syncthreads();

    // y[row] = relu(x . lin_w[row,:] + lin_b[row]), 2 threads per row
    {
        const int row = tid >> 1, hf = tid & 1;
        const float* lw = lin_w + (size_t)row * (2 * DD) + hf * DD;
        const float* xv = x_l + hf * DD;
        float dot = 0.f;
        #pragma unroll 4
        for (int k4 = 0; k4 < DD / 4; ++k4) {
            float4 xx = ld4(&xv[k4 * 4]);
            float4 wv = ld4(&lw[k4 * 4]);
            dot += xx.x * wv.x + xx.y * wv.y + xx.z * wv.z + xx.w * wv.w;
        }
        dot += __shfl_xor(dot, 1, 64);
        if (hf == 0)
            Y[(size_t)b * DD + row] = fmaxf(dot + lin_b[row], 0.f);
    }
}

// ---------------------------------------------------------------------------
// BN stats (biased variance) + apply
// ---------------------------------------------------------------------------
__global__ void bn_stats(const float* __restrict__ Y, float* __restrict__ stats)
{
    int d = blockIdx.x, t = threadIdx.x;  // 64 threads
    float s = 0.f, ss = 0.f;
    for (int b = t; b < NB; b += 64) {
        float v = Y[(size_t)b * DD + d];
        s += v; ss += v * v;
    }
    #pragma unroll
    for (int m = 32; m >= 1; m >>= 1) {
        s  += __shfl_xor(s, m, 64);
        ss += __shfl_xor(ss, m, 64);
    }
    if (t == 0) {
        float mean = s * (1.f / NB);
        float var  = ss * (1.f / NB) - mean * mean;
        stats[d]      = mean;
        stats[DD + d] = rsqrtf(var + 1e-5f);
    }
}

__global__ void bn_apply(float* __restrict__ Y, const float* __restrict__ stats,
                         const float* __restrict__ gamma, const float* __restrict__ beta)
{
    int b = blockIdx.x, t = threadIdx.x;
    float mean = stats[t], inv = stats[DD + t];
    float v = Y[(size_t)b * DD + t];
    Y[(size_t)b * DD + t] = gamma[t] * (v - mean) * inv + beta[t];
}

extern "C" void kernel_launch(void* const* d_in, const int* in_sizes, int n_in,
                              void* d_out, int out_size, void* d_ws, size_t ws_size,
                              hipStream_t stream)
{
    const float* drug_table = (const float*)d_in[0];
    const float* rela_table = (const float*)d_in[1];
    const float* ent_table  = (const float*)d_in[2];
    const float* W1         = (const float*)d_in[3];
    const float* b1         = (const float*)d_in[4];
    const float* W2         = (const float*)d_in[5];
    const float* b2         = (const float*)d_in[6];
    const float* lin_w      = (const float*)d_in[7];
    const float* lin_b      = (const float*)d_in[8];
    const float* bn_g       = (const float*)d_in[9];
    const float* bn_b       = (const float*)d_in[10];
    const int*   drug_name  = (const int*)d_in[11];
    const int*   adj_tail   = (const int*)d_in[12];
    const int*   adj_rel    = (const int*)d_in[13];
    float* out = (float*)d_out;

    float* w2s   = (float*)d_ws;               // NB*DD
    float* b2s   = w2s + (size_t)NB * DD;      // NN
    float* stats = b2s + NN;                   // 2*DD

    sum_rows<<<2 * NB + 1, 256, 0, stream>>>(W2, b2, w2s, b2s);
    gnn_main<<<NB, 512, 0, stream>>>(drug_table, rela_table, ent_table,
                                     W1, b1, lin_w, lin_b,
                                     drug_name, adj_tail, adj_rel,
                                     w2s, b2s, out);
    bn_stats<<<DD, 64, 0, stream>>>(out, stats);
    bn_apply<<<NB, DD, 0, stream>>>(out, stats, bn_g, bn_b);
}